// Round 1
// baseline (142.075 us; speedup 1.0000x reference)
//
#include <hip/hip_runtime.h>
#include <stdint.h>

#define B_ 4
#define N_ 512
#define F_ 64
#define R_ 128
#define PPI 511          // pairs per i = N-1
#define TI 4             // i's per block (= waves per block)
#define TJ 128           // j's per block
#define VSTR 136         // bf16 row stride in LDS (128 + 8 pad; 272B = 17*16B)

typedef __bf16 bf16x8 __attribute__((ext_vector_type(8)));
typedef float f32x4 __attribute__((ext_vector_type(4)));

__device__ __forceinline__ uint32_t pk_bf16x2(float lo, float hi) {
  uint32_t a = __builtin_bit_cast(uint32_t, lo);
  uint32_t b = __builtin_bit_cast(uint32_t, hi);
  a += 0x7fffu + ((a >> 16) & 1u);
  b += 0x7fffu + ((b >> 16) & 1u);
  return (a >> 16) | (b & 0xffff0000u);
}
__device__ __forceinline__ uint16_t bf16_rne(float x) {
  uint32_t a = __builtin_bit_cast(uint32_t, x);
  a += 0x7fffu + ((a >> 16) & 1u);
  return (uint16_t)(a >> 16);
}
__device__ __forceinline__ float bf_lo(uint32_t w) { return __builtin_bit_cast(float, w << 16); }
__device__ __forceinline__ float bf_hi(uint32_t w) { return __builtin_bit_cast(float, w & 0xffff0000u); }

__device__ __forceinline__ uint32_t relu_add_pk(uint32_t vv, uint32_t uu) {
  float x0 = fmaxf(bf_lo(vv) + bf_lo(uu), 0.f);
  float x1 = fmaxf(bf_hi(vv) + bf_hi(uu), 0.f);
  return pk_bf16x2(x0, x1);
}

// ---------------- P1: U'[b,i,r] = relu-input a-half (incl. b1), V[b,j,r] = b-half ----------------
// grid 256 blocks x 128 threads; each block handles 8 (b,i) rows.
__global__ __launch_bounds__(128) void prep_uv(
    const float* __restrict__ feat, const float* __restrict__ W1,
    const float* __restrict__ b1, uint16_t* __restrict__ U, uint16_t* __restrict__ V) {
  __shared__ float fs[8][F_];
  const int row0 = blockIdx.x * 8;  // global row = b*N_ + i
  const int tid = threadIdx.x;
  for (int l = tid; l < 8 * F_; l += 128) fs[l >> 6][l & 63] = feat[row0 * F_ + l];
  __syncthreads();
  const int r = tid;  // 0..127
  float aU[8], aV[8];
  const float bias = b1[r];
#pragma unroll
  for (int ii = 0; ii < 8; ++ii) { aU[ii] = bias; aV[ii] = 0.f; }
  for (int f = 0; f < F_; ++f) {
    const float wa = W1[f * R_ + r];
    const float wb = W1[(F_ + f) * R_ + r];
#pragma unroll
    for (int ii = 0; ii < 8; ++ii) {
      aU[ii] = fmaf(fs[ii][f], wa, aU[ii]);
      aV[ii] = fmaf(fs[ii][f], wb, aV[ii]);
    }
  }
#pragma unroll
  for (int ii = 0; ii < 8; ++ii) {
    U[(row0 + ii) * R_ + r] = bf16_rne(aU[ii]);
    V[(row0 + ii) * R_ + r] = bf16_rne(aV[ii]);
  }
}

// ---------------- P2: pack W2^T into A-fragment order (bf16) ----------------
// dst[((t*4+c)*64 + lane)*8 + jj] = W2[r*128 + s], r = 32c + (lane>>4)*8 + jj, s = 16t + (lane&15)
__global__ __launch_bounds__(256) void prep_w2(const float* __restrict__ W2,
                                               uint16_t* __restrict__ w2f) {
  const int d = blockIdx.x * 256 + threadIdx.x;  // 0..16383
  const int jj = d & 7, lane = (d >> 3) & 63, tc = d >> 9;
  const int c = tc & 3, t = tc >> 2;
  const int rr = 32 * c + (lane >> 4) * 8 + jj;
  const int s = 16 * t + (lane & 15);
  w2f[d] = bf16_rne(W2[rr * R_ + s]);
}

// ---------------- Main fused kernel ----------------
// grid: B_ * (N_/TI) * (N_/TJ) = 2048 blocks of 256 threads (4 waves).
// Block = (b, i0..i0+3, j0..j0+127). Wave w owns i = i0+w; loops 8 j-tiles of 16.
__global__ __launch_bounds__(256, 2) void relnet_main(
    const uint16_t* __restrict__ U, const uint16_t* __restrict__ V,
    const uint16_t* __restrict__ w2f, const float* __restrict__ b2,
    const float* __restrict__ W3, const float* __restrict__ b3,
    float* __restrict__ out) {
  __shared__ __align__(16) uint16_t Vs[TJ * VSTR];
  __shared__ __align__(16) uint16_t Us[TI * VSTR];

  const int bid = blockIdx.x;
  const int jb = bid & 3, ib = (bid >> 2) & 127, b = bid >> 9;
  const int i0 = ib * TI, j0 = jb * TJ;
  const int tid = threadIdx.x;

  // stage V rows j0..j0+127 and U rows i0..i0+3 (bf16, padded stride)
  {
    const uint4* sv = (const uint4*)(V + (b * N_ + j0) * R_);
    for (int l = tid; l < TJ * 16; l += 256) {
      const int row = l >> 4, seg = l & 15;
      *(uint4*)&Vs[row * VSTR + seg * 8] = sv[row * 16 + seg];
    }
    const uint4* su = (const uint4*)(U + (b * N_ + i0) * R_);
    for (int l = tid; l < TI * 16; l += 256) {
      const int row = l >> 4, seg = l & 15;
      *(uint4*)&Us[row * VSTR + seg * 8] = su[row * 16 + seg];
    }
  }

  const int lane = tid & 63, wave = tid >> 6;
  const int quad = lane >> 4, l4 = lane & 15;
  const int i = i0 + wave;

  // W2^T A-frags -> registers (coalesced dwordx4; 32 frags = 128 VGPRs)
  bf16x8 w2r[8][4];
#pragma unroll
  for (int t = 0; t < 8; ++t)
#pragma unroll
    for (int c = 0; c < 4; ++c) {
      const uint4 w = *(const uint4*)(w2f + ((size_t)((t * 4 + c) * 64 + lane)) * 8);
      w2r[t][c] = __builtin_bit_cast(bf16x8, w);
    }

  // per-lane epilogue constants: s = 16t + 4*quad + reg, packed bf16x2
  uint32_t b2pk[8][2], w3pk[8][2];
#pragma unroll
  for (int t = 0; t < 8; ++t)
#pragma unroll
    for (int h = 0; h < 2; ++h) {
      const int s0 = 16 * t + 4 * quad + 2 * h;
      b2pk[t][h] = pk_bf16x2(b2[s0], b2[s0 + 1]);
      w3pk[t][h] = pk_bf16x2(W3[s0], W3[s0 + 1]);
    }
  const float b3v = b3[0];

  __syncthreads();

  // u' frags for this wave's i (loop-invariant)
  uint4 ufr[4];
#pragma unroll
  for (int c = 0; c < 4; ++c)
    ufr[c] = *(const uint4*)&Us[wave * VSTR + c * 32 + quad * 8];

  for (int jt = 0; jt < 8; ++jt) {
    // build h1 B-frags: B[k = 32c + quad*8 + jj][n = l4] = relu(u'[k] + v_j[k])
    bf16x8 hb[4];
#pragma unroll
    for (int c = 0; c < 4; ++c) {
      const uint4 v = *(const uint4*)&Vs[(jt * 16 + l4) * VSTR + c * 32 + quad * 8];
      uint4 r;
      r.x = relu_add_pk(v.x, ufr[c].x);
      r.y = relu_add_pk(v.y, ufr[c].y);
      r.z = relu_add_pk(v.z, ufr[c].z);
      r.w = relu_add_pk(v.w, ufr[c].w);
      hb[c] = __builtin_bit_cast(bf16x8, r);
    }

    f32x4 acc[8];
#pragma unroll
    for (int t = 0; t < 8; ++t) acc[t] = (f32x4){0.f, 0.f, 0.f, 0.f};
#pragma unroll
    for (int c = 0; c < 4; ++c)
#pragma unroll
      for (int t = 0; t < 8; ++t)
        acc[t] = __builtin_amdgcn_mfma_f32_16x16x32_bf16(w2r[t][c], hb[c], acc[t], 0, 0, 0);

    // layer3: in-lane over (t,reg): s = 16t + 4*quad + reg
    float tot = 0.f;
#pragma unroll
    for (int t = 0; t < 8; ++t) {
      float h0 = fmaxf(acc[t][0] + bf_lo(b2pk[t][0]), 0.f);
      float h1 = fmaxf(acc[t][1] + bf_hi(b2pk[t][0]), 0.f);
      float h2 = fmaxf(acc[t][2] + bf_lo(b2pk[t][1]), 0.f);
      float h3 = fmaxf(acc[t][3] + bf_hi(b2pk[t][1]), 0.f);
      tot = fmaf(h0, bf_lo(w3pk[t][0]), tot);
      tot = fmaf(h1, bf_hi(w3pk[t][0]), tot);
      tot = fmaf(h2, bf_lo(w3pk[t][1]), tot);
      tot = fmaf(h3, bf_hi(w3pk[t][1]), tot);
    }
    tot += __shfl_xor(tot, 16, 64);
    tot += __shfl_xor(tot, 32, 64);

    if (lane < 16) {
      const int j = j0 + jt * 16 + lane;
      if (j != i) {
        const int p = (b * N_ + i) * PPI + (j < i ? j : j - 1);
        out[p] = tot + b3v;
      }
    }
  }
}

extern "C" void kernel_launch(void* const* d_in, const int* in_sizes, int n_in,
                              void* d_out, int out_size, void* d_ws, size_t ws_size,
                              hipStream_t stream) {
  const float* feat = (const float*)d_in[0];
  const float* W1 = (const float*)d_in[1];
  const float* b1 = (const float*)d_in[2];
  const float* W2 = (const float*)d_in[3];
  const float* b2 = (const float*)d_in[4];
  const float* W3 = (const float*)d_in[5];
  const float* b3 = (const float*)d_in[6];

  uint16_t* U = (uint16_t*)d_ws;                 // B*N*R bf16 = 512 KiB
  uint16_t* V = U + (size_t)B_ * N_ * R_;        // 512 KiB
  uint16_t* w2f = V + (size_t)B_ * N_ * R_;      // 32 KiB

  prep_uv<<<(B_ * N_) / 8, 128, 0, stream>>>(feat, W1, b1, U, V);
  prep_w2<<<(R_ * R_) / 256, 256, 0, stream>>>(W2, w2f);
  relnet_main<<<B_ * (N_ / TI) * (N_ / TJ), 256, 0, stream>>>(U, V, w2f, b2, W3, b3,
                                                              (float*)d_out);
}

// Round 3
// 107.272 us; speedup vs baseline: 1.3244x; 1.3244x over previous
//
#include <hip/hip_runtime.h>
#include <stdint.h>

#define B_ 4
#define N_ 512
#define F_ 64
#define R_ 128
#define PPI 511          // pairs per i = N-1
#define TI 4             // i's per block (= waves per block)
#define TJ 128           // j's per block
#define VSTR 136         // fp16 row stride in LDS (128 + 8 pad; 272B = 17*16B)

typedef _Float16 f16x8 __attribute__((ext_vector_type(8)));
typedef _Float16 f16x2 __attribute__((ext_vector_type(2)));
typedef float f32x4 __attribute__((ext_vector_type(4)));

__device__ __forceinline__ uint16_t f16bits(float x) {
  return __builtin_bit_cast(uint16_t, (_Float16)x);
}
__device__ __forceinline__ f16x2 cvt_pk(float a, float b) {
  return __builtin_bit_cast(f16x2, __builtin_amdgcn_cvt_pkrtz(a, b));
}

// ---------------- fused prep ----------------
// blocks [0,256): U'[b,i,r] = feat_i @ W1[:F] + b1 ; V[b,j,r] = feat_j @ W1[F:]
//   8 rows per block, 256 threads (tid>>7 picks row quartet, tid&127 = r).
// blocks [256,320): pack W2^T into fp16 A-fragment order:
//   dst[((t*4+c)*64+lane)*8+jj] = W2[(32c+(lane>>4)*8+jj)*R + 16t+(lane&15)]
__global__ __launch_bounds__(256) void prep_all(
    const float* __restrict__ feat, const float* __restrict__ W1,
    const float* __restrict__ b1, const float* __restrict__ W2,
    uint16_t* __restrict__ U, uint16_t* __restrict__ V, uint16_t* __restrict__ w2f) {
  if (blockIdx.x >= 256) {
    const int d = (blockIdx.x - 256) * 256 + threadIdx.x;  // 0..16383
    const int jj = d & 7, lane = (d >> 3) & 63, tc = d >> 9;
    const int c = tc & 3, t = tc >> 2;
    const int rr = 32 * c + (lane >> 4) * 8 + jj;
    const int s = 16 * t + (lane & 15);
    w2f[d] = f16bits(W2[rr * R_ + s]);
    return;
  }
  __shared__ float fs[8][F_];
  const int row0 = blockIdx.x * 8;  // global row = b*N_ + i
  const int tid = threadIdx.x;
  for (int l = tid; l < 8 * F_; l += 256) fs[l >> 6][l & 63] = feat[row0 * F_ + l];
  __syncthreads();
  const int r = tid & 127, rh = tid >> 7;  // rh -> rows 4rh..4rh+3
  float aU[4], aV[4];
  const float bias = b1[r];
#pragma unroll
  for (int ii = 0; ii < 4; ++ii) { aU[ii] = bias; aV[ii] = 0.f; }
  for (int f = 0; f < F_; ++f) {
    const float wa = W1[f * R_ + r];
    const float wb = W1[(F_ + f) * R_ + r];
#pragma unroll
    for (int ii = 0; ii < 4; ++ii) {
      aU[ii] = fmaf(fs[rh * 4 + ii][f], wa, aU[ii]);
      aV[ii] = fmaf(fs[rh * 4 + ii][f], wb, aV[ii]);
    }
  }
#pragma unroll
  for (int ii = 0; ii < 4; ++ii) {
    const int row = row0 + rh * 4 + ii;
    U[row * R_ + r] = f16bits(aU[ii]);
    V[row * R_ + r] = f16bits(aV[ii]);
  }
}

// ---------------- Main fused kernel ----------------
// grid: B_ * (N_/TI) * (N_/TJ) = 2048 blocks of 256 threads (4 waves).
// Block = (b, i0..i0+3, j0..j0+127). Wave w owns i = i0+w; loops 8 j-tiles of 16.
__global__ __launch_bounds__(256, 2) void relnet_main(
    const uint16_t* __restrict__ U, const uint16_t* __restrict__ V,
    const uint16_t* __restrict__ w2f, const float* __restrict__ b2,
    const float* __restrict__ W3, const float* __restrict__ b3,
    float* __restrict__ out) {
  __shared__ __align__(16) uint16_t Vs[TJ * VSTR];
  __shared__ __align__(16) uint16_t Us[TI * VSTR];

  const int bid = blockIdx.x;
  const int jb = bid & 3, ib = (bid >> 2) & 127, b = bid >> 9;
  const int i0 = ib * TI, j0 = jb * TJ;
  const int tid = threadIdx.x;

  // stage V rows j0..j0+127 and U rows i0..i0+3 (fp16, padded stride)
  {
    const uint4* sv = (const uint4*)(V + (b * N_ + j0) * R_);
    for (int l = tid; l < TJ * 16; l += 256) {
      const int row = l >> 4, seg = l & 15;
      *(uint4*)&Vs[row * VSTR + seg * 8] = sv[row * 16 + seg];
    }
    const uint4* su = (const uint4*)(U + (b * N_ + i0) * R_);
    for (int l = tid; l < TI * 16; l += 256) {
      const int row = l >> 4, seg = l & 15;
      *(uint4*)&Us[row * VSTR + seg * 8] = su[row * 16 + seg];
    }
  }

  const int lane = tid & 63, wave = tid >> 6;
  const int quad = lane >> 4, l4 = lane & 15;
  const int i = i0 + wave;

  // W2^T A-frags -> registers (coalesced dwordx4; 32 frags = 128 regs)
  f16x8 w2r[8][4];
#pragma unroll
  for (int t = 0; t < 8; ++t)
#pragma unroll
    for (int c = 0; c < 4; ++c) {
      const uint4 w = *(const uint4*)(w2f + ((size_t)((t * 4 + c) * 64 + lane)) * 8);
      w2r[t][c] = __builtin_bit_cast(f16x8, w);
    }

  // per-lane epilogue constants, packed fp16: s = 16t + 4*quad + 2h + {0,1}
  f16x2 b2p[8][2], w3p[8][2];
#pragma unroll
  for (int t = 0; t < 8; ++t)
#pragma unroll
    for (int h = 0; h < 2; ++h) {
      const int s0 = 16 * t + 4 * quad + 2 * h;
      b2p[t][h] = (f16x2){(_Float16)b2[s0], (_Float16)b2[s0 + 1]};
      w3p[t][h] = (f16x2){(_Float16)W3[s0], (_Float16)W3[s0 + 1]};
    }
  const float b3v = b3[0];

  __syncthreads();

  // u' frags for this wave's i (loop-invariant)
  f16x8 uf[4];
#pragma unroll
  for (int c = 0; c < 4; ++c)
    uf[c] = __builtin_bit_cast(f16x8, *(const uint4*)&Us[wave * VSTR + c * 32 + quad * 8]);

  const f16x8 z8 = {};
  const f16x2 z2 = {};

#pragma unroll 2
  for (int jt = 0; jt < 8; ++jt) {
    // h1 B-frags: B[k = 32c + quad*8 + jj][n = l4] = relu(u'[k] + v_j[k])
    // packed: 4x v_pk_add_f16 + 4x v_pk_max_f16 per chunk
    f16x8 hb[4];
#pragma unroll
    for (int c = 0; c < 4; ++c) {
      const uint4 v = *(const uint4*)&Vs[(jt * 16 + l4) * VSTR + c * 32 + quad * 8];
      hb[c] = __builtin_elementwise_max(__builtin_bit_cast(f16x8, v) + uf[c], z8);
    }

    f32x4 acc[8];
#pragma unroll
    for (int t = 0; t < 8; ++t) acc[t] = (f32x4){0.f, 0.f, 0.f, 0.f};
#pragma unroll
    for (int c = 0; c < 4; ++c)
#pragma unroll
      for (int t = 0; t < 8; ++t)
        acc[t] = __builtin_amdgcn_mfma_f32_16x16x32_f16(w2r[t][c], hb[c], acc[t], 0, 0, 0);

    // layer3: s = 16t + 4*quad + reg; packed relu(h2+b2) then v_dot2_f32_f16
    // 4 independent f32 accumulation chains (depth 4 each)
    float t0 = 0.f, t1 = 0.f, t2 = 0.f, t3 = 0.f;
#pragma unroll
    for (int t = 0; t < 8; t += 2) {
      f16x2 p0 = cvt_pk(acc[t][0], acc[t][1]);
      f16x2 p1 = cvt_pk(acc[t][2], acc[t][3]);
      p0 = __builtin_elementwise_max(p0 + b2p[t][0], z2);
      p1 = __builtin_elementwise_max(p1 + b2p[t][1], z2);
      t0 = __builtin_amdgcn_fdot2(p0, w3p[t][0], t0, false);
      t1 = __builtin_amdgcn_fdot2(p1, w3p[t][1], t1, false);
      f16x2 q0 = cvt_pk(acc[t + 1][0], acc[t + 1][1]);
      f16x2 q1 = cvt_pk(acc[t + 1][2], acc[t + 1][3]);
      q0 = __builtin_elementwise_max(q0 + b2p[t + 1][0], z2);
      q1 = __builtin_elementwise_max(q1 + b2p[t + 1][1], z2);
      t2 = __builtin_amdgcn_fdot2(q0, w3p[t + 1][0], t2, false);
      t3 = __builtin_amdgcn_fdot2(q1, w3p[t + 1][1], t3, false);
    }
    float tot = (t0 + t1) + (t2 + t3);
    tot += __shfl_xor(tot, 16, 64);
    tot += __shfl_xor(tot, 32, 64);

    if (lane < 16) {
      const int j = j0 + jt * 16 + lane;
      if (j != i) {
        const int p = (b * N_ + i) * PPI + (j < i ? j : j - 1);
        out[p] = tot + b3v;
      }
    }
  }
}

extern "C" void kernel_launch(void* const* d_in, const int* in_sizes, int n_in,
                              void* d_out, int out_size, void* d_ws, size_t ws_size,
                              hipStream_t stream) {
  const float* feat = (const float*)d_in[0];
  const float* W1 = (const float*)d_in[1];
  const float* b1 = (const float*)d_in[2];
  const float* W2 = (const float*)d_in[3];
  const float* b2 = (const float*)d_in[4];
  const float* W3 = (const float*)d_in[5];
  const float* b3 = (const float*)d_in[6];

  uint16_t* U = (uint16_t*)d_ws;                 // B*N*R fp16 = 512 KiB
  uint16_t* V = U + (size_t)B_ * N_ * R_;        // 512 KiB
  uint16_t* w2f = V + (size_t)B_ * N_ * R_;      // 32 KiB

  prep_all<<<256 + 64, 256, 0, stream>>>(feat, W1, b1, W2, U, V, w2f);
  relnet_main<<<B_ * (N_ / TI) * (N_ / TJ), 256, 0, stream>>>(U, V, w2f, b2, W3, b3,
                                                              (float*)d_out);
}